// Round 6
// baseline (226.916 us; speedup 1.0000x reference)
//
#include <hip/hip_runtime.h>

// RoPE: X (L=2048, D=4096, N=4) fp32 -> out same shape.
// R4: 218.65us (pow+sincosf per thread). R5: 222.55us (theta table kernel +
// HW sincos) -- NEUTRAL: transcendentals were already hidden under memory
// (64 waves/SIMD-launch x ~400 VALU cyc ~ 10us << 45us mem time). Kernel is
// memory-bound, <80us (absent from top-5; harness fills dominate bench dur).
// R6: single kernel, one double-pow per thread amortized over 8 l-rows
// (8x fewer pow calls + waves, no extra dispatch). Numerics chain unchanged:
// theta = fl32(pow(1e4, j/2048)) [matches numpy f32 power], ang = single f32
// multiply (ulp(ang)~2rad -- the rounding IS the value), double-precision
// reduction to revolutions + HW v_sin_f32/v_cos_f32 (validated R5, absmax
// 0.03125 vs thr 0.110625).

#define L_DIM 2048
#define D_DIM 4096
#define HALF 2048
#define LPT 8   // l-rows per thread

__global__ __launch_bounds__(256) void rope_kernel(const float4* __restrict__ X,
                                                   float4* __restrict__ out) {
    int idx = blockIdx.x * blockDim.x + threadIdx.x;  // 0 .. L/LPT*HALF-1
    int j = idx & (HALF - 1);     // blocks never straddle a j-window: 256|2048
    int lg = idx >> 11;           // l-group, 0..255

    // One correctly-rounded theta per thread (matches numpy f32 np.power).
    float theta = (float)pow(10000.0, (double)j * (1.0 / 2048.0));

    const double INV_TWO_PI = 0.159154943091895335768883763372514362;

#pragma unroll
    for (int i = 0; i < LPT; ++i) {
        int l = lg * LPT + i;
        float ang = (float)(l + 1) * theta;   // single f32 multiply (numpy chain)

        // (double)ang exact; t <= 3.34e6 -> frac error ~1e-9 revolutions.
        double t = (double)ang * INV_TWO_PI;
        float frac = (float)(t - floor(t));
        float s = __builtin_amdgcn_sinf(frac);  // sin(frac * 2pi)
        float c = __builtin_amdgcn_cosf(frac);  // cos(frac * 2pi)

        int base = l * D_DIM + j;   // float4 index of x1 (D_DIM f4/row... 4096
                                    // floats*4 -> 4096 float4 per row of D*N)
        float4 x1 = X[base];
        float4 x2 = X[base + HALF];

        float4 o1, o2;
        o1.x = c * x1.x - s * x2.x;
        o1.y = c * x1.y - s * x2.y;
        o1.z = c * x1.z - s * x2.z;
        o1.w = c * x1.w - s * x2.w;
        o2.x = s * x1.x + c * x2.x;
        o2.y = s * x1.y + c * x2.y;
        o2.z = s * x1.z + c * x2.z;
        o2.w = s * x1.w + c * x2.w;

        out[base] = o1;
        out[base + HALF] = o2;
    }
}

extern "C" void kernel_launch(void* const* d_in, const int* in_sizes, int n_in,
                              void* d_out, int out_size, void* d_ws, size_t ws_size,
                              hipStream_t stream) {
    const float4* X = (const float4*)d_in[0];
    float4* out = (float4*)d_out;
    int threads = (L_DIM / LPT) * HALF;    // 524,288 -> 8192 waves = 8/SIMD
    rope_kernel<<<threads / 256, 256, 0, stream>>>(X, out);
}